// Round 2
// baseline (1539.362 us; speedup 1.0000x reference)
//
#include <hip/hip_runtime.h>

#define N_NODES 32768
#define NPG_    4096
#define NB_     8
#define E_EDGES 262144
#define IN_C_   1024
#define HID_    512
#define K1_     2048
#define K2_     1024

__device__ __forceinline__ float lrelu(float v) { return v > 0.f ? v : 0.01f * v; }

// ---------------------------------------------------------------------------
// GEMM: C[N x M] = A[N x K] @ W[K x M]
// fp32, BM=128 BN=128 BK=16, 256 thr, 8x8 micro-tile.
// Per k: 4 ds_read_b128 per 64 FMA (vs 3 per 32 in the old 128x64 tile).
// ---------------------------------------------------------------------------
__global__ __launch_bounds__(256) void gemm_kernel(const float* __restrict__ A,
                                                   const float* __restrict__ W,
                                                   float* __restrict__ C,
                                                   int K, int M) {
  __shared__ float As[16][132];   // transposed A tile, +4 pad
  __shared__ float Bs[16][128];
  const int bm  = blockIdx.y * 128;
  const int bn  = blockIdx.x * 128;
  const int tid = threadIdx.x;
  const int tx  = tid & 15;   // col group (x8)
  const int ty  = tid >> 4;   // row group (x8)

  float acc[8][8];
#pragma unroll
  for (int i = 0; i < 8; ++i)
#pragma unroll
    for (int j = 0; j < 8; ++j) acc[i][j] = 0.f;

  for (int k0 = 0; k0 < K; k0 += 16) {
#pragma unroll
    for (int l = 0; l < 2; ++l) {            // A tile: 128 rows x 16 k (512 float4)
      const int f   = tid + l * 256;
      const int row = f >> 2;
      const int kq  = f & 3;
      const float4 v = *(const float4*)(A + (size_t)(bm + row) * K + k0 + kq * 4);
      As[kq * 4 + 0][row] = v.x;
      As[kq * 4 + 1][row] = v.y;
      As[kq * 4 + 2][row] = v.z;
      As[kq * 4 + 3][row] = v.w;
    }
#pragma unroll
    for (int l = 0; l < 2; ++l) {            // B tile: 16 k x 128 cols (512 float4)
      const int f  = tid + l * 256;
      const int kr = f >> 5;
      const int cq = f & 31;
      *(float4*)&Bs[kr][cq * 4] =
          *(const float4*)(W + (size_t)(k0 + kr) * M + bn + cq * 4);
    }
    __syncthreads();
#pragma unroll
    for (int k = 0; k < 16; ++k) {
      float a[8], b[8];
      *(float4*)&a[0] = *(const float4*)&As[k][ty * 8];
      *(float4*)&a[4] = *(const float4*)&As[k][ty * 8 + 4];
      *(float4*)&b[0] = *(const float4*)&Bs[k][tx * 8];
      *(float4*)&b[4] = *(const float4*)&Bs[k][tx * 8 + 4];
#pragma unroll
      for (int i = 0; i < 8; ++i)
#pragma unroll
        for (int j = 0; j < 8; ++j) acc[i][j] += a[i] * b[j];
    }
    __syncthreads();
  }
#pragma unroll
  for (int i = 0; i < 8; ++i) {
    *(float4*)(C + (size_t)(bm + ty * 8 + i) * M + bn + tx * 8)     = *(float4*)&acc[i][0];
    *(float4*)(C + (size_t)(bm + ty * 8 + i) * M + bn + tx * 8 + 4) = *(float4*)&acc[i][4];
  }
}

// ---------------------------------------------------------------------------
// CSR build (counting sort by dst) — edges are fixed, rebuilt each launch
// ---------------------------------------------------------------------------
__global__ void csr_count_kernel(const int* __restrict__ dst, int* __restrict__ cnt) {
  const int e = blockIdx.x * blockDim.x + threadIdx.x;
  if (e < E_EDGES) atomicAdd(&cnt[dst[e]], 1);
}

__global__ __launch_bounds__(1024) void exscan_kernel(const int* __restrict__ cnt,
                                                      int* __restrict__ ofs,
                                                      int* __restrict__ cur) {
  __shared__ int part[1024];
  const int t = threadIdx.x;
  const int base = t * 32;
  int loc[32];
  int s = 0;
#pragma unroll
  for (int i = 0; i < 32; ++i) { loc[i] = cnt[base + i]; s += loc[i]; }
  part[t] = s;
  __syncthreads();
  for (int off = 1; off < 1024; off <<= 1) {
    const int v = (t >= off) ? part[t - off] : 0;
    __syncthreads();
    part[t] += v;
    __syncthreads();
  }
  int run = (t > 0) ? part[t - 1] : 0;
#pragma unroll
  for (int i = 0; i < 32; ++i) { ofs[base + i] = run; cur[base + i] = run; run += loc[i]; }
  if (t == 1023) ofs[N_NODES] = run;
}

__global__ void csr_fill_kernel(const int* __restrict__ src, const int* __restrict__ dst,
                                int* __restrict__ cur, int* __restrict__ csr_src) {
  const int e = blockIdx.x * blockDim.x + threadIdx.x;
  if (e < E_EDGES) {
    const int p = atomicAdd(&cur[dst[e]], 1);
    csr_src[p] = src[e];
  }
}

// ---------------------------------------------------------------------------
// Degree / symmetric-normalization.  dinv[n] > 0  <=>  m[n] == 1
// ---------------------------------------------------------------------------
__global__ void dinv_kernel(const int* __restrict__ ofs, const int* __restrict__ csr,
                            const float* __restrict__ m, float* __restrict__ dinv) {
  const int n = blockIdx.x * blockDim.x + threadIdx.x;
  if (n >= N_NODES) return;
  const float mn = m[n];
  float d = mn;
  if (mn > 0.f) {
    const int s = ofs[n], e = ofs[n + 1];
    for (int i = s; i < e; ++i) d += m[csr[i]];
  }
  dinv[n] = d > 0.f ? 1.f / sqrtf(d) : 0.f;
}

// ---------------------------------------------------------------------------
// GCN aggregation: out = sum_in h[src]*dinv[src]*dinv[dst] + dinv^2*h + b, lrelu
// one block per node, 128 threads = 512 channels as float4
// ---------------------------------------------------------------------------
__global__ __launch_bounds__(128) void gcn_agg_kernel(const float* __restrict__ h,
                                                      const int* __restrict__ ofs,
                                                      const int* __restrict__ csr,
                                                      const float* __restrict__ dinv,
                                                      const float* __restrict__ bias,
                                                      float* __restrict__ out) {
  const int n = blockIdx.x;
  const int t = threadIdx.x;
  const float dn = dinv[n];
  float4 acc = {0.f, 0.f, 0.f, 0.f};
  if (dn > 0.f) {
    const int s = ofs[n], e = ofs[n + 1];
    for (int i = s; i < e; ++i) {
      const int sv = csr[i];
      const float c = dinv[sv] * dn;      // 0 when src inactive (emask folded in)
      if (c != 0.f) {
        const float4 hv = *(const float4*)(h + (size_t)sv * HID_ + t * 4);
        acc.x += c * hv.x; acc.y += c * hv.y; acc.z += c * hv.z; acc.w += c * hv.w;
      }
    }
  }
  const float4 hv = *(const float4*)(h + (size_t)n * HID_ + t * 4);
  const float4 bv = *(const float4*)(bias + t * 4);
  const float sc = dn * dn;               // = dinv^2 * nmask (dn==0 if inactive)
  float4 r;
  r.x = lrelu(acc.x + sc * hv.x + bv.x);
  r.y = lrelu(acc.y + sc * hv.y + bv.y);
  r.z = lrelu(acc.z + sc * hv.z + bv.z);
  r.w = lrelu(acc.w + sc * hv.w + bv.w);
  *(float4*)(out + (size_t)n * HID_ + t * 4) = r;
}

// ---------------------------------------------------------------------------
// SAGPool scores.  score[n] = sum_{e:dst=n} sr[src]*m[src] + so[n] + br
// where sr = x.wr, so = x.wo  (per-node dots; one wave per node)
// ---------------------------------------------------------------------------
__global__ __launch_bounds__(64) void node_dots_kernel(const float* __restrict__ h,
                                                       const float* __restrict__ wr,
                                                       const float* __restrict__ wo,
                                                       float* __restrict__ sr,
                                                       float* __restrict__ so) {
  const int n = blockIdx.x;
  const int t = threadIdx.x;
  const float4 h0 = *(const float4*)(h + (size_t)n * HID_ + t * 8);
  const float4 h1 = *(const float4*)(h + (size_t)n * HID_ + t * 8 + 4);
  const float4 r0 = *(const float4*)(wr + t * 8);
  const float4 r1 = *(const float4*)(wr + t * 8 + 4);
  const float4 o0 = *(const float4*)(wo + t * 8);
  const float4 o1 = *(const float4*)(wo + t * 8 + 4);
  float pr = h0.x * r0.x + h0.y * r0.y + h0.z * r0.z + h0.w * r0.w +
             h1.x * r1.x + h1.y * r1.y + h1.z * r1.z + h1.w * r1.w;
  float po = h0.x * o0.x + h0.y * o0.y + h0.z * o0.z + h0.w * o0.w +
             h1.x * o1.x + h1.y * o1.y + h1.z * o1.z + h1.w * o1.w;
#pragma unroll
  for (int off = 32; off; off >>= 1) {
    pr += __shfl_down(pr, off);
    po += __shfl_down(po, off);
  }
  if (t == 0) { sr[n] = pr; so[n] = po; }
}

__global__ void score_kernel(const int* __restrict__ ofs, const int* __restrict__ csr,
                             const float* __restrict__ sr, const float* __restrict__ so,
                             const float* __restrict__ m, const float* __restrict__ br,
                             float* __restrict__ score) {
  const int n = blockIdx.x * blockDim.x + threadIdx.x;
  if (n >= N_NODES) return;
  if (m[n] <= 0.f) { score[n] = -1e30f; return; }
  float s = 0.f;
  const int st = ofs[n], e = ofs[n + 1];
  for (int i = st; i < e; ++i) { const int sv = csr[i]; s += sr[sv] * m[sv]; }
  score[n] = s + so[n] + br[0];
}

// ---------------------------------------------------------------------------
// Exact stable-argsort top-k per graph: rank by count-compare in LDS.
// rank(i) = #{j: s[j]>s[i]} + #{j<i: s[j]==s[i]}  — matches double-argsort.
// ---------------------------------------------------------------------------
__global__ __launch_bounds__(256) void topk_kernel(const float* __restrict__ score,
                                                   const float* __restrict__ m,
                                                   float* __restrict__ mout, int k) {
  __shared__ float ssc[NPG_];
  const int g   = blockIdx.x >> 4;
  const int blk = blockIdx.x & 15;
  const float* gs = score + g * NPG_;
  for (int i = threadIdx.x; i < NPG_; i += 256) ssc[i] = gs[i];
  __syncthreads();
  const int li = blk * 256 + threadIdx.x;
  const float mysc = ssc[li];
  int cnt = 0;
#pragma unroll 4
  for (int j = 0; j < NPG_; ++j) {
    const float sj = ssc[j];
    cnt += (sj > mysc) || (sj == mysc && j < li);
  }
  const int n = g * NPG_ + li;
  mout[n] = (cnt < k && m[n] > 0.f) ? 1.f : 0.f;
}

__global__ void pool_apply_kernel(const float* __restrict__ xin,
                                  const float* __restrict__ score,
                                  const float* __restrict__ keep,
                                  float* __restrict__ xout) {
  const int i = blockIdx.x * blockDim.x + threadIdx.x;  // over N*HID/4
  const int n = i >> 7;
  const float f = keep[n] > 0.f ? tanhf(score[n]) : 0.f;
  float4 v = *(const float4*)(xin + (size_t)i * 4);
  v.x *= f; v.y *= f; v.z *= f; v.w *= f;
  *(float4*)(xout + (size_t)i * 4) = v;
}

// ---------------------------------------------------------------------------
// Global mean/max pool, 2-stage for parallelism
// ---------------------------------------------------------------------------
__global__ __launch_bounds__(512) void gpool1_kernel(const float* __restrict__ h,
                                                     const float* __restrict__ m,
                                                     float* __restrict__ psum,
                                                     float* __restrict__ pmax,
                                                     float* __restrict__ pcnt) {
  const int b = blockIdx.y;
  const int c = blockIdx.x;    // chunk of 128 nodes
  const int ch = threadIdx.x;
  const int base = b * NPG_ + c * 128;
  float s = 0.f, mx = -INFINITY, cv = 0.f;
  for (int i = 0; i < 128; ++i) {
    const float mv = m[base + i];
    const float hv = h[(size_t)(base + i) * HID_ + ch];
    s += mv * hv;
    if (mv > 0.f) mx = fmaxf(mx, hv);
    cv += mv;
  }
  const int p = b * 32 + c;
  psum[(size_t)p * HID_ + ch] = s;
  pmax[(size_t)p * HID_ + ch] = mx;
  if (ch == 0) pcnt[p] = cv;
}

__global__ __launch_bounds__(512) void gpool2_kernel(const float* __restrict__ psum,
                                                     const float* __restrict__ pmax,
                                                     const float* __restrict__ pcnt,
                                                     float* __restrict__ g) {
  const int b = blockIdx.x;
  const int ch = threadIdx.x;
  float s = 0.f, mx = -INFINITY, cv = 0.f;
  for (int c = 0; c < 32; ++c) {
    const int p = b * 32 + c;
    s += psum[(size_t)p * HID_ + ch];
    mx = fmaxf(mx, pmax[(size_t)p * HID_ + ch]);
    cv += pcnt[p];
  }
  g[b * 1024 + ch] = s / cv;
  g[b * 1024 + 512 + ch] = mx;
}

// ---------------------------------------------------------------------------
// Head: fc1 (1024->512) + lrelu split over (graph, 64-col chunk) blocks,
// then fc2 (512->4) one small block per graph.
// ---------------------------------------------------------------------------
__global__ __launch_bounds__(64) void fc1_kernel(const float* __restrict__ g,
                                                 const float* __restrict__ w1,
                                                 const float* __restrict__ b1,
                                                 float* __restrict__ hbuf) {
  const int b = blockIdx.x;          // graph
  const int j = blockIdx.y * 64 + threadIdx.x;
  __shared__ float gs[2 * HID_];
  for (int i = threadIdx.x; i < 2 * HID_; i += 64) gs[i] = g[b * 1024 + i];
  __syncthreads();
  float s = b1[j];
#pragma unroll 4
  for (int i = 0; i < 2 * HID_; ++i) s += gs[i] * w1[i * HID_ + j];
  hbuf[b * HID_ + j] = lrelu(s);
}

__global__ __launch_bounds__(64) void fc2_kernel(const float* __restrict__ hbuf,
                                                 const float* __restrict__ w2,
                                                 const float* __restrict__ b2,
                                                 float* __restrict__ out) {
  const int b = blockIdx.x;
  const int t = threadIdx.x;
  float s0 = 0.f, s1 = 0.f, s2 = 0.f, s3 = 0.f;
  for (int i = t; i < HID_; i += 64) {
    const float hv = hbuf[b * HID_ + i];
    s0 += hv * w2[i * 4 + 0];
    s1 += hv * w2[i * 4 + 1];
    s2 += hv * w2[i * 4 + 2];
    s3 += hv * w2[i * 4 + 3];
  }
#pragma unroll
  for (int off = 32; off; off >>= 1) {
    s0 += __shfl_down(s0, off); s1 += __shfl_down(s1, off);
    s2 += __shfl_down(s2, off); s3 += __shfl_down(s3, off);
  }
  if (t == 0) {
    out[b * 4 + 0] = s0 + b2[0];
    out[b * 4 + 1] = s1 + b2[1];
    out[b * 4 + 2] = s2 + b2[2];
    out[b * 4 + 3] = s3 + b2[3];
  }
}

__global__ void set_ones_kernel(float* __restrict__ p, int n) {
  const int i = blockIdx.x * blockDim.x + threadIdx.x;
  if (i < n) p[i] = 1.f;
}

// ---------------------------------------------------------------------------
extern "C" void kernel_launch(void* const* d_in, const int* in_sizes, int n_in,
                              void* d_out, int out_size, void* d_ws, size_t ws_size,
                              hipStream_t stream) {
  const float* x        = (const float*)d_in[0];
  const int*   edge_src = (const int*)d_in[1];
  const int*   edge_dst = (const int*)d_in[2];
  const float* W1 = (const float*)d_in[3];
  const float* b1 = (const float*)d_in[4];
  const float* p1_wr = (const float*)d_in[5];
  const float* p1_br = (const float*)d_in[6];
  const float* p1_wo = (const float*)d_in[7];
  const float* W2 = (const float*)d_in[8];
  const float* b2 = (const float*)d_in[9];
  const float* p2_wr = (const float*)d_in[10];
  const float* p2_br = (const float*)d_in[11];
  const float* p2_wo = (const float*)d_in[12];
  const float* W3 = (const float*)d_in[13];
  const float* b3 = (const float*)d_in[14];
  const float* fc1_w = (const float*)d_in[15];
  const float* fc1_b = (const float*)d_in[16];
  const float* fc2_w = (const float*)d_in[17];
  const float* fc2_b = (const float*)d_in[18];
  float* out = (float*)d_out;

  // workspace carve-up
  size_t o = 0;
  auto alloc = [&](size_t bytes) {
    void* p = (char*)d_ws + o;
    o += (bytes + 255) & ~(size_t)255;
    return p;
  };
  float* bufA  = (float*)alloc((size_t)N_NODES * HID_ * 4);
  float* bufB  = (float*)alloc((size_t)N_NODES * HID_ * 4);
  int*   csr   = (int*)alloc((size_t)E_EDGES * 4);
  int*   ofs   = (int*)alloc((size_t)(N_NODES + 1) * 4);
  int*   cur   = (int*)alloc((size_t)N_NODES * 4);
  int*   cnt   = (int*)alloc((size_t)N_NODES * 4);
  float* dinvB = (float*)alloc((size_t)N_NODES * 4);
  float* mA    = (float*)alloc((size_t)N_NODES * 4);
  float* mB    = (float*)alloc((size_t)N_NODES * 4);
  float* srB   = (float*)alloc((size_t)N_NODES * 4);
  float* soB   = (float*)alloc((size_t)N_NODES * 4);
  float* scB   = (float*)alloc((size_t)N_NODES * 4);
  float* psum  = (float*)alloc((size_t)NB_ * 32 * HID_ * 4);
  float* pmax  = (float*)alloc((size_t)NB_ * 32 * HID_ * 4);
  float* pcnt  = (float*)alloc((size_t)NB_ * 32 * 4);
  float* gbuf  = (float*)alloc((size_t)NB_ * 1024 * 4);
  float* hbuf  = (float*)alloc((size_t)NB_ * HID_ * 4);

  // ---- CSR (by dst) -------------------------------------------------------
  hipMemsetAsync(cnt, 0, (size_t)N_NODES * 4, stream);
  csr_count_kernel<<<E_EDGES / 256, 256, 0, stream>>>(edge_dst, cnt);
  exscan_kernel<<<1, 1024, 0, stream>>>(cnt, ofs, cur);
  csr_fill_kernel<<<E_EDGES / 256, 256, 0, stream>>>(edge_src, edge_dst, cur, csr);
  set_ones_kernel<<<N_NODES / 256, 256, 0, stream>>>(mA, N_NODES);

  const dim3 gemm_grid(HID_ / 128, N_NODES / 128);

  // ---- Layer 1: GCN(1024->512) + pool K1 ---------------------------------
  gemm_kernel<<<gemm_grid, 256, 0, stream>>>(x, W1, bufA, IN_C_, HID_);
  dinv_kernel<<<N_NODES / 256, 256, 0, stream>>>(ofs, csr, mA, dinvB);
  gcn_agg_kernel<<<N_NODES, 128, 0, stream>>>(bufA, ofs, csr, dinvB, b1, bufB);
  node_dots_kernel<<<N_NODES, 64, 0, stream>>>(bufB, p1_wr, p1_wo, srB, soB);
  score_kernel<<<N_NODES / 256, 256, 0, stream>>>(ofs, csr, srB, soB, mA, p1_br, scB);
  topk_kernel<<<NB_ * 16, 256, 0, stream>>>(scB, mA, mB, K1_);
  pool_apply_kernel<<<(N_NODES * HID_ / 4) / 256, 256, 0, stream>>>(bufB, scB, mB, bufA);

  // ---- Layer 2: GCN(512->512) + pool K2  (mask = mB) ----------------------
  gemm_kernel<<<gemm_grid, 256, 0, stream>>>(bufA, W2, bufB, HID_, HID_);
  dinv_kernel<<<N_NODES / 256, 256, 0, stream>>>(ofs, csr, mB, dinvB);
  gcn_agg_kernel<<<N_NODES, 128, 0, stream>>>(bufB, ofs, csr, dinvB, b2, bufA);
  node_dots_kernel<<<N_NODES, 64, 0, stream>>>(bufA, p2_wr, p2_wo, srB, soB);
  score_kernel<<<N_NODES / 256, 256, 0, stream>>>(ofs, csr, srB, soB, mB, p2_br, scB);
  topk_kernel<<<NB_ * 16, 256, 0, stream>>>(scB, mB, mA, K2_);
  pool_apply_kernel<<<(N_NODES * HID_ / 4) / 256, 256, 0, stream>>>(bufA, scB, mA, bufB);

  // ---- Layer 3: GCN(512->512)  (mask = mA) --------------------------------
  gemm_kernel<<<gemm_grid, 256, 0, stream>>>(bufB, W3, bufA, HID_, HID_);
  dinv_kernel<<<N_NODES / 256, 256, 0, stream>>>(ofs, csr, mA, dinvB);
  gcn_agg_kernel<<<N_NODES, 128, 0, stream>>>(bufA, ofs, csr, dinvB, b3, bufB);

  // ---- Global pool + head -------------------------------------------------
  gpool1_kernel<<<dim3(32, NB_), 512, 0, stream>>>(bufB, mA, psum, pmax, pcnt);
  gpool2_kernel<<<NB_, 512, 0, stream>>>(psum, pmax, pcnt, gbuf);
  fc1_kernel<<<dim3(NB_, HID_ / 64), 64, 0, stream>>>(gbuf, fc1_w, fc1_b, hbuf);
  fc2_kernel<<<NB_, 64, 0, stream>>>(hbuf, fc2_w, fc2_b, out);
}

// Round 3
// 1008.509 us; speedup vs baseline: 1.5264x; 1.5264x over previous
//
#include <hip/hip_runtime.h>

#define N_NODES 32768
#define NPG_    4096
#define NB_     8
#define E_EDGES 262144
#define IN_C_   1024
#define HID_    512
#define NOUT_   512
#define K1_     2048
#define K2_     1024

typedef _Float16 half4_t __attribute__((ext_vector_type(4)));
typedef _Float16 half8_t __attribute__((ext_vector_type(8)));
typedef float    floatx4 __attribute__((ext_vector_type(4)));

__device__ __forceinline__ float lrelu(float v) { return v > 0.f ? v : 0.01f * v; }

// ---------------------------------------------------------------------------
// Split-fp16 MFMA GEMM:  C[M x 512] = A[M x K] @ W[K x 512]   (fp32-accurate)
// A,B split as hi+lo fp16 (residual <= 2^-24|x|); C = Ah*Bh + Ah*Bl + Al*Bh.
// B pre-split AND pre-transposed to [512][K] so A/B tiles share one layout.
// Tile 128x128, BK=64 f16-k, 4 waves (2x2), 4x4 16x16x32 frags per wave.
// LDS: 4 x [128][64] fp16 = 64 KB, XOR swizzle slot^=(row&7) -> floor-rate b128.
// ---------------------------------------------------------------------------
template <bool AFP32>
__global__ __launch_bounds__(256) void gemm_split_kernel(
    const float* __restrict__ A32,
    const _Float16* __restrict__ Ah, const _Float16* __restrict__ Al,
    const _Float16* __restrict__ Bh, const _Float16* __restrict__ Bl,
    float* __restrict__ C, int K) {
  __shared__ __align__(16) _Float16 sAh[128][64];
  __shared__ __align__(16) _Float16 sAl[128][64];
  __shared__ __align__(16) _Float16 sBh[128][64];
  __shared__ __align__(16) _Float16 sBl[128][64];

  const int t    = threadIdx.x;
  const int bm   = blockIdx.y * 128;
  const int bn   = blockIdx.x * 128;
  const int lane = t & 63;
  const int wv   = t >> 6;
  const int wr   = wv >> 1;      // wave row 0..1 (64 rows each)
  const int wc   = wv & 1;       // wave col 0..1
  const int fr   = lane & 15;    // row (A) / col (B) within 16-frag
  const int kg   = lane >> 4;    // k-group 0..3

  floatx4 zero = {0.f, 0.f, 0.f, 0.f};
  floatx4 acc[4][4];
#pragma unroll
  for (int i = 0; i < 4; ++i)
#pragma unroll
    for (int j = 0; j < 4; ++j) acc[i][j] = zero;

  for (int kt = 0; kt < K; kt += 64) {
    // ---- stage B (pre-split, transposed [n][k]) ----
#pragma unroll
    for (int l = 0; l < 4; ++l) {
      const int idx = l * 256 + t;
      const int row = idx >> 3;          // n within tile
      const int slot = idx & 7;          // 8-elem k-slot
      const int col = ((slot ^ (row & 7)) << 3);
      *(half8_t*)&sBh[row][col] = *(const half8_t*)(Bh + (size_t)(bn + row) * K + kt + slot * 8);
      *(half8_t*)&sBl[row][col] = *(const half8_t*)(Bl + (size_t)(bn + row) * K + kt + slot * 8);
    }
    // ---- stage A ----
    if constexpr (AFP32) {
      // fp32 source, split on the fly
#pragma unroll
      for (int l = 0; l < 8; ++l) {
        const int idx = l * 256 + t;
        const int row = idx >> 4;        // 16 float4 per row
        const int c4  = idx & 15;
        const float4 v = *(const float4*)(A32 + (size_t)(bm + row) * K + kt + c4 * 4);
        const _Float16 h0 = (_Float16)v.x, h1 = (_Float16)v.y,
                       h2 = (_Float16)v.z, h3 = (_Float16)v.w;
        half4_t hh = {h0, h1, h2, h3};
        half4_t hl = {(_Float16)(v.x - (float)h0), (_Float16)(v.y - (float)h1),
                      (_Float16)(v.z - (float)h2), (_Float16)(v.w - (float)h3)};
        const int slot = c4 >> 1;
        const int col  = ((slot ^ (row & 7)) << 3) + (c4 & 1) * 4;
        *(half4_t*)&sAh[row][col] = hh;
        *(half4_t*)&sAl[row][col] = hl;
      }
    } else {
#pragma unroll
      for (int l = 0; l < 4; ++l) {
        const int idx = l * 256 + t;
        const int row = idx >> 3;
        const int slot = idx & 7;
        const int col = ((slot ^ (row & 7)) << 3);
        *(half8_t*)&sAh[row][col] = *(const half8_t*)(Ah + (size_t)(bm + row) * K + kt + slot * 8);
        *(half8_t*)&sAl[row][col] = *(const half8_t*)(Al + (size_t)(bm + row) * K + kt + slot * 8);
      }
    }
    __syncthreads();

#pragma unroll
    for (int ks = 0; ks < 2; ++ks) {
      half8_t ahf[4], alf[4], bhf[4], blf[4];
      const int slot = ks * 4 + kg;
#pragma unroll
      for (int i = 0; i < 4; ++i) {
        const int row = wr * 64 + i * 16 + fr;
        const int col = ((slot ^ (row & 7)) << 3);
        ahf[i] = *(const half8_t*)&sAh[row][col];
        alf[i] = *(const half8_t*)&sAl[row][col];
      }
#pragma unroll
      for (int j = 0; j < 4; ++j) {
        const int nrow = wc * 64 + j * 16 + fr;
        const int col  = ((slot ^ (nrow & 7)) << 3);
        bhf[j] = *(const half8_t*)&sBh[nrow][col];
        blf[j] = *(const half8_t*)&sBl[nrow][col];
      }
#pragma unroll
      for (int i = 0; i < 4; ++i)
#pragma unroll
        for (int j = 0; j < 4; ++j) {
          acc[i][j] = __builtin_amdgcn_mfma_f32_16x16x32_f16(ahf[i], bhf[j], acc[i][j], 0, 0, 0);
          acc[i][j] = __builtin_amdgcn_mfma_f32_16x16x32_f16(ahf[i], blf[j], acc[i][j], 0, 0, 0);
          acc[i][j] = __builtin_amdgcn_mfma_f32_16x16x32_f16(alf[i], bhf[j], acc[i][j], 0, 0, 0);
        }
    }
    __syncthreads();
  }

  // epilogue: C/D layout col=lane&15, row=(lane>>4)*4+reg  [m89/m91 verified]
#pragma unroll
  for (int i = 0; i < 4; ++i)
#pragma unroll
    for (int j = 0; j < 4; ++j) {
      const int row0 = bm + wr * 64 + i * 16 + kg * 4;
      const int col  = bn + wc * 64 + j * 16 + fr;
#pragma unroll
      for (int r = 0; r < 4; ++r)
        C[(size_t)(row0 + r) * NOUT_ + col] = acc[i][j][r];
    }
}

// ---------------------------------------------------------------------------
// Weight split + transpose:  W[K x 512] fp32  ->  Wht,Wlt [512 x K] fp16
// ---------------------------------------------------------------------------
__global__ void split_w_kernel(const float* __restrict__ W, int K, int total,
                               _Float16* __restrict__ Wht, _Float16* __restrict__ Wlt) {
  const int idx = blockIdx.x * blockDim.x + threadIdx.x;   // over 512*K
  if (idx >= total) return;
  const int n = idx / K;
  const int k = idx - n * K;
  const float v = W[(size_t)k * NOUT_ + n];
  const _Float16 h = (_Float16)v;
  Wht[idx] = h;
  Wlt[idx] = (_Float16)(v - (float)h);
}

// ---------------------------------------------------------------------------
// CSR build (counting sort by dst) — edges are fixed, rebuilt each launch
// ---------------------------------------------------------------------------
__global__ void csr_count_kernel(const int* __restrict__ dst, int* __restrict__ cnt) {
  const int e = blockIdx.x * blockDim.x + threadIdx.x;
  if (e < E_EDGES) atomicAdd(&cnt[dst[e]], 1);
}

__global__ __launch_bounds__(1024) void exscan_kernel(const int* __restrict__ cnt,
                                                      int* __restrict__ ofs,
                                                      int* __restrict__ cur) {
  __shared__ int part[1024];
  const int t = threadIdx.x;
  const int base = t * 32;
  int loc[32];
  int s = 0;
#pragma unroll
  for (int i = 0; i < 32; ++i) { loc[i] = cnt[base + i]; s += loc[i]; }
  part[t] = s;
  __syncthreads();
  for (int off = 1; off < 1024; off <<= 1) {
    const int v = (t >= off) ? part[t - off] : 0;
    __syncthreads();
    part[t] += v;
    __syncthreads();
  }
  int run = (t > 0) ? part[t - 1] : 0;
#pragma unroll
  for (int i = 0; i < 32; ++i) { ofs[base + i] = run; cur[base + i] = run; run += loc[i]; }
  if (t == 1023) ofs[N_NODES] = run;
}

__global__ void csr_fill_kernel(const int* __restrict__ src, const int* __restrict__ dst,
                                int* __restrict__ cur, int* __restrict__ csr_src) {
  const int e = blockIdx.x * blockDim.x + threadIdx.x;
  if (e < E_EDGES) {
    const int p = atomicAdd(&cur[dst[e]], 1);
    csr_src[p] = src[e];
  }
}

// ---------------------------------------------------------------------------
// Degree / symmetric-normalization.  dinv[n] > 0  <=>  m[n] == 1
// ---------------------------------------------------------------------------
__global__ void dinv_kernel(const int* __restrict__ ofs, const int* __restrict__ csr,
                            const float* __restrict__ m, float* __restrict__ dinv) {
  const int n = blockIdx.x * blockDim.x + threadIdx.x;
  if (n >= N_NODES) return;
  const float mn = m[n];
  float d = mn;
  if (mn > 0.f) {
    const int s = ofs[n], e = ofs[n + 1];
    for (int i = s; i < e; ++i) d += m[csr[i]];
  }
  dinv[n] = d > 0.f ? 1.f / sqrtf(d) : 0.f;
}

// ---------------------------------------------------------------------------
// GCN aggregation: out = sum_in h[src]*dinv[src]*dinv[dst] + dinv^2*h + b, lrelu
// ---------------------------------------------------------------------------
__global__ __launch_bounds__(128) void gcn_agg_kernel(const float* __restrict__ h,
                                                      const int* __restrict__ ofs,
                                                      const int* __restrict__ csr,
                                                      const float* __restrict__ dinv,
                                                      const float* __restrict__ bias,
                                                      float* __restrict__ out) {
  const int n = blockIdx.x;
  const int t = threadIdx.x;
  const float dn = dinv[n];
  float4 acc = {0.f, 0.f, 0.f, 0.f};
  if (dn > 0.f) {
    const int s = ofs[n], e = ofs[n + 1];
    for (int i = s; i < e; ++i) {
      const int sv = csr[i];
      const float c = dinv[sv] * dn;      // 0 when src inactive (emask folded in)
      if (c != 0.f) {
        const float4 hv = *(const float4*)(h + (size_t)sv * HID_ + t * 4);
        acc.x += c * hv.x; acc.y += c * hv.y; acc.z += c * hv.z; acc.w += c * hv.w;
      }
    }
  }
  const float4 hv = *(const float4*)(h + (size_t)n * HID_ + t * 4);
  const float4 bv = *(const float4*)(bias + t * 4);
  const float sc = dn * dn;
  float4 r;
  r.x = lrelu(acc.x + sc * hv.x + bv.x);
  r.y = lrelu(acc.y + sc * hv.y + bv.y);
  r.z = lrelu(acc.z + sc * hv.z + bv.z);
  r.w = lrelu(acc.w + sc * hv.w + bv.w);
  *(float4*)(out + (size_t)n * HID_ + t * 4) = r;
}

// ---------------------------------------------------------------------------
// SAGPool scores.  score[n] = sum_{e:dst=n} sr[src]*m[src] + so[n] + br
// ---------------------------------------------------------------------------
__global__ __launch_bounds__(64) void node_dots_kernel(const float* __restrict__ h,
                                                       const float* __restrict__ wr,
                                                       const float* __restrict__ wo,
                                                       float* __restrict__ sr,
                                                       float* __restrict__ so) {
  const int n = blockIdx.x;
  const int t = threadIdx.x;
  const float4 h0 = *(const float4*)(h + (size_t)n * HID_ + t * 8);
  const float4 h1 = *(const float4*)(h + (size_t)n * HID_ + t * 8 + 4);
  const float4 r0 = *(const float4*)(wr + t * 8);
  const float4 r1 = *(const float4*)(wr + t * 8 + 4);
  const float4 o0 = *(const float4*)(wo + t * 8);
  const float4 o1 = *(const float4*)(wo + t * 8 + 4);
  float pr = h0.x * r0.x + h0.y * r0.y + h0.z * r0.z + h0.w * r0.w +
             h1.x * r1.x + h1.y * r1.y + h1.z * r1.z + h1.w * r1.w;
  float po = h0.x * o0.x + h0.y * o0.y + h0.z * o0.z + h0.w * o0.w +
             h1.x * o1.x + h1.y * o1.y + h1.z * o1.z + h1.w * o1.w;
#pragma unroll
  for (int off = 32; off; off >>= 1) {
    pr += __shfl_down(pr, off);
    po += __shfl_down(po, off);
  }
  if (t == 0) { sr[n] = pr; so[n] = po; }
}

__global__ void score_kernel(const int* __restrict__ ofs, const int* __restrict__ csr,
                             const float* __restrict__ sr, const float* __restrict__ so,
                             const float* __restrict__ m, const float* __restrict__ br,
                             float* __restrict__ score) {
  const int n = blockIdx.x * blockDim.x + threadIdx.x;
  if (n >= N_NODES) return;
  if (m[n] <= 0.f) { score[n] = -1e30f; return; }
  float s = 0.f;
  const int st = ofs[n], e = ofs[n + 1];
  for (int i = st; i < e; ++i) { const int sv = csr[i]; s += sr[sv] * m[sv]; }
  score[n] = s + so[n] + br[0];
}

// ---------------------------------------------------------------------------
// Exact stable-argsort top-k per graph (count-compare in LDS)
// ---------------------------------------------------------------------------
__global__ __launch_bounds__(256) void topk_kernel(const float* __restrict__ score,
                                                   const float* __restrict__ m,
                                                   float* __restrict__ mout, int k) {
  __shared__ float ssc[NPG_];
  const int g   = blockIdx.x >> 4;
  const int blk = blockIdx.x & 15;
  const float* gs = score + g * NPG_;
  for (int i = threadIdx.x; i < NPG_; i += 256) ssc[i] = gs[i];
  __syncthreads();
  const int li = blk * 256 + threadIdx.x;
  const float mysc = ssc[li];
  int cnt = 0;
#pragma unroll 4
  for (int j = 0; j < NPG_; ++j) {
    const float sj = ssc[j];
    cnt += (sj > mysc) || (sj == mysc && j < li);
  }
  const int n = g * NPG_ + li;
  mout[n] = (cnt < k && m[n] > 0.f) ? 1.f : 0.f;
}

// ---------------------------------------------------------------------------
// pool_apply + split: x2 = x*tanh(score)*keep, written directly as hi/lo fp16
// (pool output feeds only the next GEMM)
// ---------------------------------------------------------------------------
__global__ void pool_apply_split_kernel(const float* __restrict__ xin,
                                        const float* __restrict__ score,
                                        const float* __restrict__ keep,
                                        _Float16* __restrict__ Ph,
                                        _Float16* __restrict__ Pl) {
  const int i = blockIdx.x * blockDim.x + threadIdx.x;  // over N*HID/4
  const int n = i >> 7;
  const float f = keep[n] > 0.f ? tanhf(score[n]) : 0.f;
  const float4 v = *(const float4*)(xin + (size_t)i * 4);
  const float x0 = v.x * f, x1 = v.y * f, x2 = v.z * f, x3 = v.w * f;
  const _Float16 h0 = (_Float16)x0, h1 = (_Float16)x1,
                 h2 = (_Float16)x2, h3 = (_Float16)x3;
  half4_t hh = {h0, h1, h2, h3};
  half4_t hl = {(_Float16)(x0 - (float)h0), (_Float16)(x1 - (float)h1),
                (_Float16)(x2 - (float)h2), (_Float16)(x3 - (float)h3)};
  *(half4_t*)(Ph + (size_t)i * 4) = hh;
  *(half4_t*)(Pl + (size_t)i * 4) = hl;
}

// ---------------------------------------------------------------------------
// Global mean/max pool, 2-stage
// ---------------------------------------------------------------------------
__global__ __launch_bounds__(512) void gpool1_kernel(const float* __restrict__ h,
                                                     const float* __restrict__ m,
                                                     float* __restrict__ psum,
                                                     float* __restrict__ pmax,
                                                     float* __restrict__ pcnt) {
  const int b = blockIdx.y;
  const int c = blockIdx.x;
  const int ch = threadIdx.x;
  const int base = b * NPG_ + c * 128;
  float s = 0.f, mx = -INFINITY, cv = 0.f;
  for (int i = 0; i < 128; ++i) {
    const float mv = m[base + i];
    const float hv = h[(size_t)(base + i) * HID_ + ch];
    s += mv * hv;
    if (mv > 0.f) mx = fmaxf(mx, hv);
    cv += mv;
  }
  const int p = b * 32 + c;
  psum[(size_t)p * HID_ + ch] = s;
  pmax[(size_t)p * HID_ + ch] = mx;
  if (ch == 0) pcnt[p] = cv;
}

__global__ __launch_bounds__(512) void gpool2_kernel(const float* __restrict__ psum,
                                                     const float* __restrict__ pmax,
                                                     const float* __restrict__ pcnt,
                                                     float* __restrict__ g) {
  const int b = blockIdx.x;
  const int ch = threadIdx.x;
  float s = 0.f, mx = -INFINITY, cv = 0.f;
  for (int c = 0; c < 32; ++c) {
    const int p = b * 32 + c;
    s += psum[(size_t)p * HID_ + ch];
    mx = fmaxf(mx, pmax[(size_t)p * HID_ + ch]);
    cv += pcnt[p];
  }
  g[b * 1024 + ch] = s / cv;
  g[b * 1024 + 512 + ch] = mx;
}

// ---------------------------------------------------------------------------
// Head
// ---------------------------------------------------------------------------
__global__ __launch_bounds__(64) void fc1_kernel(const float* __restrict__ g,
                                                 const float* __restrict__ w1,
                                                 const float* __restrict__ b1,
                                                 float* __restrict__ hbuf) {
  const int b = blockIdx.x;
  const int j = blockIdx.y * 64 + threadIdx.x;
  __shared__ float gs[2 * HID_];
  for (int i = threadIdx.x; i < 2 * HID_; i += 64) gs[i] = g[b * 1024 + i];
  __syncthreads();
  float s = b1[j];
#pragma unroll 4
  for (int i = 0; i < 2 * HID_; ++i) s += gs[i] * w1[i * HID_ + j];
  hbuf[b * HID_ + j] = lrelu(s);
}

__global__ __launch_bounds__(64) void fc2_kernel(const float* __restrict__ hbuf,
                                                 const float* __restrict__ w2,
                                                 const float* __restrict__ b2,
                                                 float* __restrict__ out) {
  const int b = blockIdx.x;
  const int t = threadIdx.x;
  float s0 = 0.f, s1 = 0.f, s2 = 0.f, s3 = 0.f;
  for (int i = t; i < HID_; i += 64) {
    const float hv = hbuf[b * HID_ + i];
    s0 += hv * w2[i * 4 + 0];
    s1 += hv * w2[i * 4 + 1];
    s2 += hv * w2[i * 4 + 2];
    s3 += hv * w2[i * 4 + 3];
  }
#pragma unroll
  for (int off = 32; off; off >>= 1) {
    s0 += __shfl_down(s0, off); s1 += __shfl_down(s1, off);
    s2 += __shfl_down(s2, off); s3 += __shfl_down(s3, off);
  }
  if (t == 0) {
    out[b * 4 + 0] = s0 + b2[0];
    out[b * 4 + 1] = s1 + b2[1];
    out[b * 4 + 2] = s2 + b2[2];
    out[b * 4 + 3] = s3 + b2[3];
  }
}

__global__ void set_ones_kernel(float* __restrict__ p, int n) {
  const int i = blockIdx.x * blockDim.x + threadIdx.x;
  if (i < n) p[i] = 1.f;
}

// ---------------------------------------------------------------------------
extern "C" void kernel_launch(void* const* d_in, const int* in_sizes, int n_in,
                              void* d_out, int out_size, void* d_ws, size_t ws_size,
                              hipStream_t stream) {
  const float* x        = (const float*)d_in[0];
  const int*   edge_src = (const int*)d_in[1];
  const int*   edge_dst = (const int*)d_in[2];
  const float* W1 = (const float*)d_in[3];
  const float* b1 = (const float*)d_in[4];
  const float* p1_wr = (const float*)d_in[5];
  const float* p1_br = (const float*)d_in[6];
  const float* p1_wo = (const float*)d_in[7];
  const float* W2 = (const float*)d_in[8];
  const float* b2 = (const float*)d_in[9];
  const float* p2_wr = (const float*)d_in[10];
  const float* p2_br = (const float*)d_in[11];
  const float* p2_wo = (const float*)d_in[12];
  const float* W3 = (const float*)d_in[13];
  const float* b3 = (const float*)d_in[14];
  const float* fc1_w = (const float*)d_in[15];
  const float* fc1_b = (const float*)d_in[16];
  const float* fc2_w = (const float*)d_in[17];
  const float* fc2_b = (const float*)d_in[18];
  float* out = (float*)d_out;

  // ---- workspace carve-up (R0/R1 ping-pong keeps total ~= baseline) -------
  size_t o = 0;
  auto alloc = [&](size_t bytes) {
    void* p = (char*)d_ws + o;
    o += (bytes + 255) & ~(size_t)255;
    return p;
  };
  float* R0 = (float*)alloc((size_t)N_NODES * HID_ * 4);   // 64 MB
  float* R1 = (float*)alloc((size_t)N_NODES * HID_ * 4);   // 64 MB
  _Float16* W1ht = (_Float16*)alloc((size_t)NOUT_ * IN_C_ * 2);
  _Float16* W1lt = (_Float16*)alloc((size_t)NOUT_ * IN_C_ * 2);
  _Float16* W2ht = (_Float16*)alloc((size_t)NOUT_ * HID_ * 2);
  _Float16* W2lt = (_Float16*)alloc((size_t)NOUT_ * HID_ * 2);
  _Float16* W3ht = (_Float16*)alloc((size_t)NOUT_ * HID_ * 2);
  _Float16* W3lt = (_Float16*)alloc((size_t)NOUT_ * HID_ * 2);
  int*   csr   = (int*)alloc((size_t)E_EDGES * 4);
  int*   ofs   = (int*)alloc((size_t)(N_NODES + 1) * 4);
  int*   cur   = (int*)alloc((size_t)N_NODES * 4);
  int*   cnt   = (int*)alloc((size_t)N_NODES * 4);
  float* dinvB = (float*)alloc((size_t)N_NODES * 4);
  float* mA    = (float*)alloc((size_t)N_NODES * 4);
  float* mB    = (float*)alloc((size_t)N_NODES * 4);
  float* srB   = (float*)alloc((size_t)N_NODES * 4);
  float* soB   = (float*)alloc((size_t)N_NODES * 4);
  float* scB   = (float*)alloc((size_t)N_NODES * 4);
  float* psum  = (float*)alloc((size_t)NB_ * 32 * HID_ * 4);
  float* pmax  = (float*)alloc((size_t)NB_ * 32 * HID_ * 4);
  float* pcnt  = (float*)alloc((size_t)NB_ * 32 * 4);
  float* gbuf  = (float*)alloc((size_t)NB_ * 1024 * 4);
  float* hbuf  = (float*)alloc((size_t)NB_ * HID_ * 4);

  // fp16 aliases of the ping-pong regions (dead fp32 data gets overwritten)
  _Float16* P1h = (_Float16*)R0;                              // pool1 out
  _Float16* P1l = P1h + (size_t)N_NODES * HID_;
  _Float16* P2h = (_Float16*)R1;                              // pool2 out
  _Float16* P2l = P2h + (size_t)N_NODES * HID_;

  // ---- CSR (by dst) + weight splits ---------------------------------------
  hipMemsetAsync(cnt, 0, (size_t)N_NODES * 4, stream);
  csr_count_kernel<<<E_EDGES / 256, 256, 0, stream>>>(edge_dst, cnt);
  exscan_kernel<<<1, 1024, 0, stream>>>(cnt, ofs, cur);
  csr_fill_kernel<<<E_EDGES / 256, 256, 0, stream>>>(edge_src, edge_dst, cur, csr);
  set_ones_kernel<<<N_NODES / 256, 256, 0, stream>>>(mA, N_NODES);
  split_w_kernel<<<(NOUT_ * IN_C_) / 256, 256, 0, stream>>>(W1, IN_C_, NOUT_ * IN_C_, W1ht, W1lt);
  split_w_kernel<<<(NOUT_ * HID_) / 256, 256, 0, stream>>>(W2, HID_, NOUT_ * HID_, W2ht, W2lt);
  split_w_kernel<<<(NOUT_ * HID_) / 256, 256, 0, stream>>>(W3, HID_, NOUT_ * HID_, W3ht, W3lt);

  const dim3 gemm_grid(NOUT_ / 128, N_NODES / 128);

  // ---- Layer 1: GCN(1024->512) + pool K1 ---------------------------------
  gemm_split_kernel<true><<<gemm_grid, 256, 0, stream>>>(x, nullptr, nullptr,
                                                         W1ht, W1lt, R0, IN_C_);
  dinv_kernel<<<N_NODES / 256, 256, 0, stream>>>(ofs, csr, mA, dinvB);
  gcn_agg_kernel<<<N_NODES, 128, 0, stream>>>(R0, ofs, csr, dinvB, b1, R1);
  node_dots_kernel<<<N_NODES, 64, 0, stream>>>(R1, p1_wr, p1_wo, srB, soB);
  score_kernel<<<N_NODES / 256, 256, 0, stream>>>(ofs, csr, srB, soB, mA, p1_br, scB);
  topk_kernel<<<NB_ * 16, 256, 0, stream>>>(scB, mA, mB, K1_);
  pool_apply_split_kernel<<<(N_NODES * HID_ / 4) / 256, 256, 0, stream>>>(R1, scB, mB, P1h, P1l);

  // ---- Layer 2: GCN(512->512) + pool K2  (mask = mB) ----------------------
  gemm_split_kernel<false><<<gemm_grid, 256, 0, stream>>>(nullptr, P1h, P1l,
                                                          W2ht, W2lt, R1, HID_);
  dinv_kernel<<<N_NODES / 256, 256, 0, stream>>>(ofs, csr, mB, dinvB);
  gcn_agg_kernel<<<N_NODES, 128, 0, stream>>>(R1, ofs, csr, dinvB, b2, R0);
  node_dots_kernel<<<N_NODES, 64, 0, stream>>>(R0, p2_wr, p2_wo, srB, soB);
  score_kernel<<<N_NODES / 256, 256, 0, stream>>>(ofs, csr, srB, soB, mB, p2_br, scB);
  topk_kernel<<<NB_ * 16, 256, 0, stream>>>(scB, mB, mA, K2_);
  pool_apply_split_kernel<<<(N_NODES * HID_ / 4) / 256, 256, 0, stream>>>(R0, scB, mA, P2h, P2l);

  // ---- Layer 3: GCN(512->512)  (mask = mA) --------------------------------
  gemm_split_kernel<false><<<gemm_grid, 256, 0, stream>>>(nullptr, P2h, P2l,
                                                          W3ht, W3lt, R0, HID_);
  dinv_kernel<<<N_NODES / 256, 256, 0, stream>>>(ofs, csr, mA, dinvB);
  gcn_agg_kernel<<<N_NODES, 128, 0, stream>>>(R0, ofs, csr, dinvB, b3, R1);

  // ---- Global pool + head -------------------------------------------------
  gpool1_kernel<<<dim3(32, NB_), 512, 0, stream>>>(R1, mA, psum, pmax, pcnt);
  gpool2_kernel<<<NB_, 512, 0, stream>>>(psum, pmax, pcnt, gbuf);
  fc1_kernel<<<dim3(NB_, HID_ / 64), 64, 0, stream>>>(gbuf, fc1_w, fc1_b, hbuf);
  fc2_kernel<<<NB_, 64, 0, stream>>>(hbuf, fc2_w, fc2_b, out);
}

// Round 7
// 993.581 us; speedup vs baseline: 1.5493x; 1.0150x over previous
//
#include <hip/hip_runtime.h>

#define N_NODES 32768
#define NPG_    4096
#define NB_     8
#define E_EDGES 262144
#define IN_C_   1024
#define HID_    512
#define NOUT_   512
#define K1_     2048
#define K2_     1024

typedef _Float16 half4_t __attribute__((ext_vector_type(4)));
typedef _Float16 half8_t __attribute__((ext_vector_type(8)));
typedef float    floatx4 __attribute__((ext_vector_type(4)));

__device__ __forceinline__ float lrelu(float v) { return v > 0.f ? v : 0.01f * v; }

// ---------------------------------------------------------------------------
// Split-fp16 MFMA GEMM:  C[M x 512] = (A[M x K] @ W[K x 512]) * dinv[row]
// A,B split as hi+lo fp16; C = Ah*Bh + Ah*Bl + Al*Bh  (fp32-accurate).
// Epilogue scales each row by dinv[row] -> output is hs for the agg kernel.
// 1D grid + XCD-aware swizzle (T1): the 4 N-blocks sharing an A-panel become
// temporally adjacent on ONE XCD -> A fetched once per panel (was ~2x).
// 1024 blocks % 8 XCDs == 0 -> simple remap is bijective.
// ---------------------------------------------------------------------------
template <bool AFP32>
__global__ __launch_bounds__(256) void gemm_split_kernel(
    const float* __restrict__ A32,
    const _Float16* __restrict__ Ah, const _Float16* __restrict__ Al,
    const _Float16* __restrict__ Bh, const _Float16* __restrict__ Bl,
    const float* __restrict__ dinv,
    float* __restrict__ C, int K) {
  __shared__ __align__(16) _Float16 sAh[128][64];
  __shared__ __align__(16) _Float16 sAl[128][64];
  __shared__ __align__(16) _Float16 sBh[128][64];
  __shared__ __align__(16) _Float16 sBl[128][64];

  const int t    = threadIdx.x;
  // XCD swizzle: per-XCD contiguous M-range, N fastest within
  const int nwg  = gridDim.x;                       // 1024, multiple of 8
  const int per  = nwg >> 3;
  const int id   = (blockIdx.x & 7) * per + (blockIdx.x >> 3);
  const int bn   = (id & 3) * 128;                  // 4 N-tiles
  const int bm   = (id >> 2) * 128;                 // 256 M-tiles
  const int lane = t & 63;
  const int wv   = t >> 6;
  const int wr   = wv >> 1;      // wave row 0..1 (64 rows each)
  const int wc   = wv & 1;       // wave col 0..1
  const int fr   = lane & 15;    // row (A) / col (B) within 16-frag
  const int kg   = lane >> 4;    // k-group 0..3

  floatx4 zero = {0.f, 0.f, 0.f, 0.f};
  floatx4 acc[4][4];
#pragma unroll
  for (int i = 0; i < 4; ++i)
#pragma unroll
    for (int j = 0; j < 4; ++j) acc[i][j] = zero;

  for (int kt = 0; kt < K; kt += 64) {
    // ---- stage B (pre-split, transposed [n][k]) ----
#pragma unroll
    for (int l = 0; l < 4; ++l) {
      const int idx = l * 256 + t;
      const int row = idx >> 3;          // n within tile
      const int slot = idx & 7;          // 8-elem k-slot
      const int col = ((slot ^ (row & 7)) << 3);
      *(half8_t*)&sBh[row][col] = *(const half8_t*)(Bh + (size_t)(bn + row) * K + kt + slot * 8);
      *(half8_t*)&sBl[row][col] = *(const half8_t*)(Bl + (size_t)(bn + row) * K + kt + slot * 8);
    }
    // ---- stage A ----
    if constexpr (AFP32) {
#pragma unroll
      for (int l = 0; l < 8; ++l) {
        const int idx = l * 256 + t;
        const int row = idx >> 4;        // 16 float4 per row
        const int c4  = idx & 15;
        const float4 v = *(const float4*)(A32 + (size_t)(bm + row) * K + kt + c4 * 4);
        const _Float16 h0 = (_Float16)v.x, h1 = (_Float16)v.y,
                       h2 = (_Float16)v.z, h3 = (_Float16)v.w;
        half4_t hh = {h0, h1, h2, h3};
        half4_t hl = {(_Float16)(v.x - (float)h0), (_Float16)(v.y - (float)h1),
                      (_Float16)(v.z - (float)h2), (_Float16)(v.w - (float)h3)};
        const int slot = c4 >> 1;
        const int col  = ((slot ^ (row & 7)) << 3) + (c4 & 1) * 4;
        *(half4_t*)&sAh[row][col] = hh;
        *(half4_t*)&sAl[row][col] = hl;
      }
    } else {
#pragma unroll
      for (int l = 0; l < 4; ++l) {
        const int idx = l * 256 + t;
        const int row = idx >> 3;
        const int slot = idx & 7;
        const int col = ((slot ^ (row & 7)) << 3);
        *(half8_t*)&sAh[row][col] = *(const half8_t*)(Ah + (size_t)(bm + row) * K + kt + slot * 8);
        *(half8_t*)&sAl[row][col] = *(const half8_t*)(Al + (size_t)(bm + row) * K + kt + slot * 8);
      }
    }
    __syncthreads();

#pragma unroll
    for (int ks = 0; ks < 2; ++ks) {
      half8_t ahf[4], alf[4], bhf[4], blf[4];
      const int slot = ks * 4 + kg;
#pragma unroll
      for (int i = 0; i < 4; ++i) {
        const int row = wr * 64 + i * 16 + fr;
        const int col = ((slot ^ (row & 7)) << 3);
        ahf[i] = *(const half8_t*)&sAh[row][col];
        alf[i] = *(const half8_t*)&sAl[row][col];
      }
#pragma unroll
      for (int j = 0; j < 4; ++j) {
        const int nrow = wc * 64 + j * 16 + fr;
        const int col  = ((slot ^ (nrow & 7)) << 3);
        bhf[j] = *(const half8_t*)&sBh[nrow][col];
        blf[j] = *(const half8_t*)&sBl[nrow][col];
      }
#pragma unroll
      for (int i = 0; i < 4; ++i)
#pragma unroll
        for (int j = 0; j < 4; ++j) {
          acc[i][j] = __builtin_amdgcn_mfma_f32_16x16x32_f16(ahf[i], bhf[j], acc[i][j], 0, 0, 0);
          acc[i][j] = __builtin_amdgcn_mfma_f32_16x16x32_f16(ahf[i], blf[j], acc[i][j], 0, 0, 0);
          acc[i][j] = __builtin_amdgcn_mfma_f32_16x16x32_f16(alf[i], bhf[j], acc[i][j], 0, 0, 0);
        }
    }
    __syncthreads();
  }

  // epilogue: C/D layout col=lane&15, row=(lane>>4)*4+reg; scale by dinv[row]
#pragma unroll
  for (int i = 0; i < 4; ++i) {
    const int row0 = bm + wr * 64 + i * 16 + kg * 4;
    float ds[4];
#pragma unroll
    for (int r = 0; r < 4; ++r) ds[r] = dinv[row0 + r];
#pragma unroll
    for (int j = 0; j < 4; ++j) {
      const int col = bn + wc * 64 + j * 16 + fr;
#pragma unroll
      for (int r = 0; r < 4; ++r)
        C[(size_t)(row0 + r) * NOUT_ + col] = acc[i][j][r] * ds[r];
    }
  }
}

// ---------------------------------------------------------------------------
// Weight split + transpose:  W[K x 512] fp32  ->  Wht,Wlt [512 x K] fp16
// ---------------------------------------------------------------------------
__global__ void split_w_kernel(const float* __restrict__ W, int K, int total,
                               _Float16* __restrict__ Wht, _Float16* __restrict__ Wlt) {
  const int idx = blockIdx.x * blockDim.x + threadIdx.x;   // over 512*K
  if (idx >= total) return;
  const int n = idx / K;
  const int k = idx - n * K;
  const float v = W[(size_t)k * NOUT_ + n];
  const _Float16 h = (_Float16)v;
  Wht[idx] = h;
  Wlt[idx] = (_Float16)(v - (float)h);
}

// ---------------------------------------------------------------------------
// CSR build (counting sort by dst)
// ---------------------------------------------------------------------------
__global__ void csr_count_kernel(const int* __restrict__ dst, int* __restrict__ cnt) {
  const int e = blockIdx.x * blockDim.x + threadIdx.x;
  if (e < E_EDGES) atomicAdd(&cnt[dst[e]], 1);
}

__global__ __launch_bounds__(1024) void exscan_kernel(const int* __restrict__ cnt,
                                                      int* __restrict__ ofs,
                                                      int* __restrict__ cur) {
  __shared__ int part[1024];
  const int t = threadIdx.x;
  const int base = t * 32;
  int loc[32];
  int s = 0;
#pragma unroll
  for (int i = 0; i < 32; ++i) { loc[i] = cnt[base + i]; s += loc[i]; }
  part[t] = s;
  __syncthreads();
  for (int off = 1; off < 1024; off <<= 1) {
    const int v = (t >= off) ? part[t - off] : 0;
    __syncthreads();
    part[t] += v;
    __syncthreads();
  }
  int run = (t > 0) ? part[t - 1] : 0;
#pragma unroll
  for (int i = 0; i < 32; ++i) { ofs[base + i] = run; cur[base + i] = run; run += loc[i]; }
  if (t == 1023) ofs[N_NODES] = run;
}

__global__ void csr_fill_kernel(const int* __restrict__ src, const int* __restrict__ dst,
                                int* __restrict__ cur, int* __restrict__ csr_src) {
  const int e = blockIdx.x * blockDim.x + threadIdx.x;
  if (e < E_EDGES) {
    const int p = atomicAdd(&cur[dst[e]], 1);
    csr_src[p] = src[e];
  }
}

// ---------------------------------------------------------------------------
// Degree / symmetric-normalization.  dinv[n] > 0  <=>  m[n] == 1
// ---------------------------------------------------------------------------
__global__ void dinv_kernel(const int* __restrict__ ofs, const int* __restrict__ csr,
                            const float* __restrict__ m, float* __restrict__ dinv) {
  const int n = blockIdx.x * blockDim.x + threadIdx.x;
  if (n >= N_NODES) return;
  const float mn = m[n];
  float d = mn;
  if (mn > 0.f) {
    const int s = ofs[n], e = ofs[n + 1];
    for (int i = s; i < e; ++i) d += m[csr[i]];
  }
  dinv[n] = d > 0.f ? 1.f / sqrtf(d) : 0.f;
}

// ---------------------------------------------------------------------------
// Fused GCN aggregation (+ optional SAGPool dots).
// hs rows are pre-scaled by dinv[src] (GEMM epilogue), so:
//   out[n] = lrelu( dinv[n]*(sum_{src in N(n)} hs[src] + hs[n]) + b )
// One wave per node: 64 lanes x 8 channels; 2-edge unroll for ILP.
// DOTS: sr[n] = out[n].wr, so[n] = out[n].wo via shfl reduce (free — row is
// already in registers), replacing the separate node_dots pass.
// ---------------------------------------------------------------------------
template <bool DOTS>
__global__ __launch_bounds__(256) void gcn_agg_fused_kernel(
    const float* __restrict__ hs,
    const int* __restrict__ ofs, const int* __restrict__ csr,
    const float* __restrict__ dinv, const float* __restrict__ bias,
    const float* __restrict__ wr, const float* __restrict__ wo,
    float* __restrict__ out, float* __restrict__ sr, float* __restrict__ so) {
  const int n = blockIdx.x * 4 + (threadIdx.x >> 6);
  const int t = threadIdx.x & 63;
  const size_t c0 = (size_t)t * 8;
  const float dn = dinv[n];
  floatx4 a0 = {0.f, 0.f, 0.f, 0.f}, a1 = a0, b0 = a0, b1 = a0;
  if (dn > 0.f) {
    const int s = ofs[n], e = ofs[n + 1];
    int i = s;
    for (; i + 2 <= e; i += 2) {
      const int s0 = csr[i], s1 = csr[i + 1];
      const floatx4 v00 = *(const floatx4*)(hs + (size_t)s0 * HID_ + c0);
      const floatx4 v01 = *(const floatx4*)(hs + (size_t)s0 * HID_ + c0 + 4);
      const floatx4 v10 = *(const floatx4*)(hs + (size_t)s1 * HID_ + c0);
      const floatx4 v11 = *(const floatx4*)(hs + (size_t)s1 * HID_ + c0 + 4);
      a0 += v00; a1 += v01; b0 += v10; b1 += v11;
    }
    if (i < e) {
      const int s0 = csr[i];
      a0 += *(const floatx4*)(hs + (size_t)s0 * HID_ + c0);
      a1 += *(const floatx4*)(hs + (size_t)s0 * HID_ + c0 + 4);
    }
    // self-loop term: + hs[n]
    a0 += *(const floatx4*)(hs + (size_t)n * HID_ + c0);
    a1 += *(const floatx4*)(hs + (size_t)n * HID_ + c0 + 4);
    a0 += b0; a1 += b1;
  }
  const floatx4 bv0 = *(const floatx4*)(bias + c0);
  const floatx4 bv1 = *(const floatx4*)(bias + c0 + 4);
  floatx4 r0, r1;
#pragma unroll
  for (int q = 0; q < 4; ++q) {
    r0[q] = lrelu(dn * a0[q] + bv0[q]);
    r1[q] = lrelu(dn * a1[q] + bv1[q]);
  }
  *(floatx4*)(out + (size_t)n * HID_ + c0)     = r0;
  *(floatx4*)(out + (size_t)n * HID_ + c0 + 4) = r1;

  if constexpr (DOTS) {
    const floatx4 wr0 = *(const floatx4*)(wr + c0);
    const floatx4 wr1 = *(const floatx4*)(wr + c0 + 4);
    const floatx4 wo0 = *(const floatx4*)(wo + c0);
    const floatx4 wo1 = *(const floatx4*)(wo + c0 + 4);
    float pr = 0.f, po = 0.f;
#pragma unroll
    for (int q = 0; q < 4; ++q) {
      pr += r0[q] * wr0[q] + r1[q] * wr1[q];
      po += r0[q] * wo0[q] + r1[q] * wo1[q];
    }
#pragma unroll
    for (int off = 32; off; off >>= 1) {
      pr += __shfl_down(pr, off);
      po += __shfl_down(po, off);
    }
    if (t == 0) { sr[n] = pr; so[n] = po; }
  }
}

__global__ void score_kernel(const int* __restrict__ ofs, const int* __restrict__ csr,
                             const float* __restrict__ sr, const float* __restrict__ so,
                             const float* __restrict__ m, const float* __restrict__ br,
                             float* __restrict__ score) {
  const int n = blockIdx.x * blockDim.x + threadIdx.x;
  if (n >= N_NODES) return;
  if (m[n] <= 0.f) { score[n] = -1e30f; return; }
  float s = 0.f;
  const int st = ofs[n], e = ofs[n + 1];
  for (int i = st; i < e; ++i) { const int sv = csr[i]; s += sr[sv] * m[sv]; }
  score[n] = s + so[n] + br[0];
}

// ---------------------------------------------------------------------------
// Exact stable-argsort top-k per graph (count-compare in LDS)
// ---------------------------------------------------------------------------
__global__ __launch_bounds__(256) void topk_kernel(const float* __restrict__ score,
                                                   const float* __restrict__ m,
                                                   float* __restrict__ mout, int k) {
  __shared__ float ssc[NPG_];
  const int g   = blockIdx.x >> 4;
  const int blk = blockIdx.x & 15;
  const float* gs = score + g * NPG_;
  for (int i = threadIdx.x; i < NPG_; i += 256) ssc[i] = gs[i];
  __syncthreads();
  const int li = blk * 256 + threadIdx.x;
  const float mysc = ssc[li];
  int cnt = 0;
#pragma unroll 4
  for (int j = 0; j < NPG_; ++j) {
    const float sj = ssc[j];
    cnt += (sj > mysc) || (sj == mysc && j < li);
  }
  const int n = g * NPG_ + li;
  mout[n] = (cnt < k && m[n] > 0.f) ? 1.f : 0.f;
}

// ---------------------------------------------------------------------------
// pool_apply + split: x2 = x*tanh(score)*keep, written directly as hi/lo fp16
// ---------------------------------------------------------------------------
__global__ void pool_apply_split_kernel(const float* __restrict__ xin,
                                        const float* __restrict__ score,
                                        const float* __restrict__ keep,
                                        _Float16* __restrict__ Ph,
                                        _Float16* __restrict__ Pl) {
  const int i = blockIdx.x * blockDim.x + threadIdx.x;  // over N*HID/4
  const int n = i >> 7;
  const float f = keep[n] > 0.f ? tanhf(score[n]) : 0.f;
  const float4 v = *(const float4*)(xin + (size_t)i * 4);
  const float x0 = v.x * f, x1 = v.y * f, x2 = v.z * f, x3 = v.w * f;
  const _Float16 h0 = (_Float16)x0, h1 = (_Float16)x1,
                 h2 = (_Float16)x2, h3 = (_Float16)x3;
  half4_t hh = {h0, h1, h2, h3};
  half4_t hl = {(_Float16)(x0 - (float)h0), (_Float16)(x1 - (float)h1),
                (_Float16)(x2 - (float)h2), (_Float16)(x3 - (float)h3)};
  *(half4_t*)(Ph + (size_t)i * 4) = hh;
  *(half4_t*)(Pl + (size_t)i * 4) = hl;
}

// ---------------------------------------------------------------------------
// Global mean/max pool, 2-stage
// ---------------------------------------------------------------------------
__global__ __launch_bounds__(512) void gpool1_kernel(const float* __restrict__ h,
                                                     const float* __restrict__ m,
                                                     float* __restrict__ psum,
                                                     float* __restrict__ pmax,
                                                     float* __restrict__ pcnt) {
  const int b = blockIdx.y;
  const int c = blockIdx.x;
  const int ch = threadIdx.x;
  const int base = b * NPG_ + c * 128;
  float s = 0.f, mx = -INFINITY, cv = 0.f;
  for (int i = 0; i < 128; ++i) {
    const float mv = m[base + i];
    const float hv = h[(size_t)(base + i) * HID_ + ch];
    s += mv * hv;
    if (mv > 0.f) mx = fmaxf(mx, hv);
    cv += mv;
  }
  const int p = b * 32 + c;
  psum[(size_t)p * HID_ + ch] = s;
  pmax[(size_t)p * HID_ + ch] = mx;
  if (ch == 0) pcnt[p] = cv;
}

__global__ __launch_bounds__(512) void gpool2_kernel(const float* __restrict__ psum,
                                                     const float* __restrict__ pmax,
                                                     const float* __restrict__ pcnt,
                                                     float* __restrict__ g) {
  const int b = blockIdx.x;
  const int ch = threadIdx.x;
  float s = 0.f, mx = -INFINITY, cv = 0.f;
  for (int c = 0; c < 32; ++c) {
    const int p = b * 32 + c;
    s += psum[(size_t)p * HID_ + ch];
    mx = fmaxf(mx, pmax[(size_t)p * HID_ + ch]);
    cv += pcnt[p];
  }
  g[b * 1024 + ch] = s / cv;
  g[b * 1024 + 512 + ch] = mx;
}

// ---------------------------------------------------------------------------
// Head
// ---------------------------------------------------------------------------
__global__ __launch_bounds__(64) void fc1_kernel(const float* __restrict__ g,
                                                 const float* __restrict__ w1,
                                                 const float* __restrict__ b1,
                                                 float* __restrict__ hbuf) {
  const int b = blockIdx.x;
  const int j = blockIdx.y * 64 + threadIdx.x;
  __shared__ float gs[2 * HID_];
  for (int i = threadIdx.x; i < 2 * HID_; i += 64) gs[i] = g[b * 1024 + i];
  __syncthreads();
  float s = b1[j];
#pragma unroll 4
  for (int i = 0; i < 2 * HID_; ++i) s += gs[i] * w1[i * HID_ + j];
  hbuf[b * HID_ + j] = lrelu(s);
}

__global__ __launch_bounds__(64) void fc2_kernel(const float* __restrict__ hbuf,
                                                 const float* __restrict__ w2,
                                                 const float* __restrict__ b2,
                                                 float* __restrict__ out) {
  const int b = blockIdx.x;
  const int t = threadIdx.x;
  float s0 = 0.f, s1 = 0.f, s2 = 0.f, s3 = 0.f;
  for (int i = t; i < HID_; i += 64) {
    const float hv = hbuf[b * HID_ + i];
    s0 += hv * w2[i * 4 + 0];
    s1 += hv * w2[i * 4 + 1];
    s2 += hv * w2[i * 4 + 2];
    s3 += hv * w2[i * 4 + 3];
  }
#pragma unroll
  for (int off = 32; off; off >>= 1) {
    s0 += __shfl_down(s0, off); s1 += __shfl_down(s1, off);
    s2 += __shfl_down(s2, off); s3 += __shfl_down(s3, off);
  }
  if (t == 0) {
    out[b * 4 + 0] = s0 + b2[0];
    out[b * 4 + 1] = s1 + b2[1];
    out[b * 4 + 2] = s2 + b2[2];
    out[b * 4 + 3] = s3 + b2[3];
  }
}

__global__ void set_ones_kernel(float* __restrict__ p, int n) {
  const int i = blockIdx.x * blockDim.x + threadIdx.x;
  if (i < n) p[i] = 1.f;
}

// ---------------------------------------------------------------------------
extern "C" void kernel_launch(void* const* d_in, const int* in_sizes, int n_in,
                              void* d_out, int out_size, void* d_ws, size_t ws_size,
                              hipStream_t stream) {
  const float* x        = (const float*)d_in[0];
  const int*   edge_src = (const int*)d_in[1];
  const int*   edge_dst = (const int*)d_in[2];
  const float* W1 = (const float*)d_in[3];
  const float* b1 = (const float*)d_in[4];
  const float* p1_wr = (const float*)d_in[5];
  const float* p1_br = (const float*)d_in[6];
  const float* p1_wo = (const float*)d_in[7];
  const float* W2 = (const float*)d_in[8];
  const float* b2 = (const float*)d_in[9];
  const float* p2_wr = (const float*)d_in[10];
  const float* p2_br = (const float*)d_in[11];
  const float* p2_wo = (const float*)d_in[12];
  const float* W3 = (const float*)d_in[13];
  const float* b3 = (const float*)d_in[14];
  const float* fc1_w = (const float*)d_in[15];
  const float* fc1_b = (const float*)d_in[16];
  const float* fc2_w = (const float*)d_in[17];
  const float* fc2_b = (const float*)d_in[18];
  float* out = (float*)d_out;

  // ---- workspace carve-up (R0/R1 ping-pong) -------------------------------
  size_t o = 0;
  auto alloc = [&](size_t bytes) {
    void* p = (char*)d_ws + o;
    o += (bytes + 255) & ~(size_t)255;
    return p;
  };
  float* R0 = (float*)alloc((size_t)N_NODES * HID_ * 4);   // 64 MB
  float* R1 = (float*)alloc((size_t)N_NODES * HID_ * 4);   // 64 MB
  _Float16* W1ht = (_Float16*)alloc((size_t)NOUT_ * IN_C_ * 2);
  _Float16* W1lt = (_Float16*)alloc((size_t)NOUT_ * IN_C_ * 2);
  _Float16* W2ht = (_Float16*)alloc((size_t)NOUT_ * HID_ * 2);
  _Float16* W2lt = (_Float16*)alloc((size_t)NOUT_ * HID_ * 2);
  _Float16* W3ht = (_Float16*)alloc((size_t)NOUT_ * HID_ * 2);
  _Float16* W3lt = (_Float16*)alloc((size_t)NOUT_ * HID_ * 2);
  int*   csr   = (int*)alloc((size_t)E_EDGES * 4);
  int*   ofs   = (int*)alloc((size_t)(N_NODES + 1) * 4);
  int*   cur   = (int*)alloc((size_t)N_NODES * 4);
  int*   cnt   = (int*)alloc((size_t)N_NODES * 4);
  float* dinvB = (float*)alloc((size_t)N_NODES * 4);
  float* mA    = (float*)alloc((size_t)N_NODES * 4);
  float* mB    = (float*)alloc((size_t)N_NODES * 4);
  float* srB   = (float*)alloc((size_t)N_NODES * 4);
  float* soB   = (float*)alloc((size_t)N_NODES * 4);
  float* scB   = (float*)alloc((size_t)N_NODES * 4);
  float* psum  = (float*)alloc((size_t)NB_ * 32 * HID_ * 4);
  float* pmax  = (float*)alloc((size_t)NB_ * 32 * HID_ * 4);
  float* pcnt  = (float*)alloc((size_t)NB_ * 32 * 4);
  float* gbuf  = (float*)alloc((size_t)NB_ * 1024 * 4);
  float* hbuf  = (float*)alloc((size_t)NB_ * HID_ * 4);

  // fp16 aliases of the ping-pong regions (dead fp32 data gets overwritten)
  _Float16* P1h = (_Float16*)R0;                              // pool1 out
  _Float16* P1l = P1h + (size_t)N_NODES * HID_;
  _Float16* P2h = (_Float16*)R1;                              // pool2 out
  _Float16* P2l = P2h + (size_t)N_NODES * HID_;

  // ---- CSR (by dst) + weight splits ---------------------------------------
  hipMemsetAsync(cnt, 0, (size_t)N_NODES * 4, stream);
  csr_count_kernel<<<E_EDGES / 256, 256, 0, stream>>>(edge_dst, cnt);
  exscan_kernel<<<1, 1024, 0, stream>>>(cnt, ofs, cur);
  csr_fill_kernel<<<E_EDGES / 256, 256, 0, stream>>>(edge_src, edge_dst, cur, csr);
  set_ones_kernel<<<N_NODES / 256, 256, 0, stream>>>(mA, N_NODES);
  split_w_kernel<<<(NOUT_ * IN_C_) / 256, 256, 0, stream>>>(W1, IN_C_, NOUT_ * IN_C_, W1ht, W1lt);
  split_w_kernel<<<(NOUT_ * HID_) / 256, 256, 0, stream>>>(W2, HID_, NOUT_ * HID_, W2ht, W2lt);
  split_w_kernel<<<(NOUT_ * HID_) / 256, 256, 0, stream>>>(W3, HID_, NOUT_ * HID_, W3ht, W3lt);

  const int gemm_grid = (NOUT_ / 128) * (N_NODES / 128);   // 1024, 1D + swizzle
  const int agg_grid = N_NODES / 4;

  // ---- Layer 1: GCN(1024->512) + pool K1 ---------------------------------
  dinv_kernel<<<N_NODES / 256, 256, 0, stream>>>(ofs, csr, mA, dinvB);
  gemm_split_kernel<true><<<gemm_grid, 256, 0, stream>>>(x, nullptr, nullptr,
                                                         W1ht, W1lt, dinvB, R0, IN_C_);
  gcn_agg_fused_kernel<true><<<agg_grid, 256, 0, stream>>>(R0, ofs, csr, dinvB, b1,
                                                           p1_wr, p1_wo, R1, srB, soB);
  score_kernel<<<N_NODES / 256, 256, 0, stream>>>(ofs, csr, srB, soB, mA, p1_br, scB);
  topk_kernel<<<NB_ * 16, 256, 0, stream>>>(scB, mA, mB, K1_);
  pool_apply_split_kernel<<<(N_NODES * HID_ / 4) / 256, 256, 0, stream>>>(R1, scB, mB, P1h, P1l);

  // ---- Layer 2: GCN(512->512) + pool K2  (mask = mB) ----------------------
  dinv_kernel<<<N_NODES / 256, 256, 0, stream>>>(ofs, csr, mB, dinvB);
  gemm_split_kernel<false><<<gemm_grid, 256, 0, stream>>>(nullptr, P1h, P1l,
                                                          W2ht, W2lt, dinvB, R1, HID_);
  gcn_agg_fused_kernel<true><<<agg_grid, 256, 0, stream>>>(R1, ofs, csr, dinvB, b2,
                                                           p2_wr, p2_wo, R0, srB, soB);
  score_kernel<<<N_NODES / 256, 256, 0, stream>>>(ofs, csr, srB, soB, mB, p2_br, scB);
  topk_kernel<<<NB_ * 16, 256, 0, stream>>>(scB, mB, mA, K2_);
  pool_apply_split_kernel<<<(N_NODES * HID_ / 4) / 256, 256, 0, stream>>>(R0, scB, mA, P2h, P2l);

  // ---- Layer 3: GCN(512->512)  (mask = mA) --------------------------------
  dinv_kernel<<<N_NODES / 256, 256, 0, stream>>>(ofs, csr, mA, dinvB);
  gemm_split_kernel<false><<<gemm_grid, 256, 0, stream>>>(nullptr, P2h, P2l,
                                                          W3ht, W3lt, dinvB, R0, HID_);
  gcn_agg_fused_kernel<false><<<agg_grid, 256, 0, stream>>>(R0, ofs, csr, dinvB, b3,
                                                            nullptr, nullptr, R1, nullptr, nullptr);

  // ---- Global pool + head -------------------------------------------------
  gpool1_kernel<<<dim3(32, NB_), 512, 0, stream>>>(R1, mA, psum, pmax, pcnt);
  gpool2_kernel<<<NB_, 512, 0, stream>>>(psum, pmax, pcnt, gbuf);
  fc1_kernel<<<dim3(NB_, HID_ / 64), 64, 0, stream>>>(gbuf, fc1_w, fc1_b, hbuf);
  fc2_kernel<<<NB_, 64, 0, stream>>>(hbuf, fc2_w, fc2_b, out);
}